// Round 6
// baseline (534.915 us; speedup 1.0000x reference)
//
#include <hip/hip_runtime.h>
#include <math.h>

// Problem constants
static constexpr int BB = 4;        // batch
static constexpr int NN = 16384;    // nodes per batch
static constexpr int KK = 8;        // neighbors per node
static constexpr int EE = 131072;   // edges per batch = NN*KK
static constexpr int RR = 65536;    // BB*NN rows
static constexpr int EG = 524288;   // BB*EE edges total

// Workspace layout (float offsets — regions sized for fp32 era, fp16 uses half)
static constexpr size_t OFF_X0 = 0;
static constexpr size_t OFF_X1 = OFF_X0 + (size_t)RR*32;
static constexpr size_t OFF_X2 = OFF_X1 + (size_t)RR*64;
static constexpr size_t OFF_X3 = OFF_X2 + (size_t)RR*128;
static constexpr size_t OFF_ZB = OFF_X3 + (size_t)RR*256; // fp16 b-branch
static constexpr size_t OFF_ZC = OFF_ZB + (size_t)RR*128; // 65536 fp32
static constexpr size_t OFF_S  = OFF_ZC + (size_t)RR;     // 9 slots * 512
static constexpr size_t OFF_SS = OFF_S + 9*512;           // 9 slots * 512
static constexpr size_t OFF_WP = OFF_SS + 9*512;          // packed fp16 weights (ushort)
static constexpr size_t WP1_OFF = 0;               // 128*32   = 4096
static constexpr size_t WP2_OFF = 4096;            // 256*64   = 16384
static constexpr size_t WP3_OFF = 4096 + 16384;    // 512*128  = 65536

__device__ __forceinline__ float lrelu(float x) { return fmaxf(x, 0.2f*x); }

__device__ __forceinline__ unsigned short f2h(float f) {
    _Float16 h = (_Float16)f;
    return *(unsigned short*)&h;
}
__device__ __forceinline__ float h2f(unsigned short u) {
    _Float16 h = *(_Float16*)&u;
    return (float)h;
}

typedef __attribute__((ext_vector_type(8))) _Float16 half8v;
typedef __attribute__((ext_vector_type(8))) unsigned short ushort8v;
typedef __attribute__((ext_vector_type(4))) float float4v;

// ---------------- layer 0: node GEMM 8->32 (pre-BN, fp16 out) + fused col stats ----------------
__global__ __launch_bounds__(256) void k_l0_node(const float* __restrict__ xf,
                                                 const float* __restrict__ W,
                                                 unsigned short* __restrict__ z,
                                                 float* __restrict__ S) {
    __shared__ float w[256];
    __shared__ float red[64];
    int tid = threadIdx.x;
    w[tid] = W[tid];
    if (tid < 64) red[tid] = 0.f;
    __syncthreads();
    int r = blockIdx.x*256 + tid;
    const float4* xr = (const float4*)(xf + (size_t)r*8);
    float4 a = xr[0], b = xr[1];
    float xv[8] = {a.x,a.y,a.z,a.w,b.x,b.y,b.z,b.w};
    float op[32];
#pragma unroll
    for (int c = 0; c < 32; ++c) {
        float s = 0.f;
#pragma unroll
        for (int k = 0; k < 8; ++k) s = fmaf(xv[k], w[k*32+c], s);
        op[c] = s;
    }
    ushort8v* zp = (ushort8v*)(z + (size_t)r*32);
#pragma unroll
    for (int i = 0; i < 4; ++i) {
        ushort8v h;
#pragma unroll
        for (int j = 0; j < 8; ++j) h[j] = f2h(op[i*8+j]);
        zp[i] = h;
    }
#pragma unroll
    for (int c = 0; c < 32; ++c) {
        float s = op[c], q = op[c]*op[c];
#pragma unroll
        for (int off = 32; off >= 1; off >>= 1) {
            s += __shfl_xor(s, off, 64);
            q += __shfl_xor(q, off, 64);
        }
        if ((tid & 63) == 0) { atomicAdd(&red[c], s); atomicAdd(&red[32+c], q); }
    }
    __syncthreads();
    if (tid < 64) atomicAdd(&S[tid], red[tid]);
}

// ---------------- column stats (only for the 1-col cat head) ----------------
template<int C>
__global__ __launch_bounds__(256) void k_colstats(const float* __restrict__ Z, int R,
                                                  float* __restrict__ S) {
    constexpr int TPC = 256 / C;
    __shared__ float ls[256];
    __shared__ float lq[256];
    int tid = threadIdx.x;
    int c = tid % C, rr = tid / C;
    float s = 0.f, q = 0.f;
    for (int r = blockIdx.x*TPC + rr; r < R; r += gridDim.x*TPC) {
        float v = Z[(size_t)r*C + c];
        s += v; q = fmaf(v, v, q);
    }
    ls[tid] = s; lq[tid] = q;
    __syncthreads();
#pragma unroll
    for (int half = TPC/2; half >= 1; half >>= 1) {
        if (rr < half) { ls[tid] += ls[tid + half*C]; lq[tid] += lq[tid + half*C]; }
        __syncthreads();
    }
    if (rr == 0) { atomicAdd(&S[c], ls[tid]); atomicAdd(&S[C+c], lq[tid]); }
}

// ---------------- finalize (two BN slots in one launch) ----------------
__global__ void k_finalize2(const float* __restrict__ Sa, const float* __restrict__ ga,
                            const float* __restrict__ ba, float invA,
                            float* __restrict__ SSa, int Ca,
                            const float* __restrict__ Sb, const float* __restrict__ gb,
                            const float* __restrict__ bb, float invB,
                            float* __restrict__ SSb, int Cb) {
    int t = threadIdx.x;
    if (t < Ca) {
        float m = Sa[t]*invA;
        float v = fmaxf(Sa[Ca+t]*invA - m*m, 0.f);
        float sc = ga[t]*rsqrtf(v + 1e-5f);
        SSa[t] = sc;
        SSa[Ca+t] = fmaf(-m, sc, ba[t]);
    }
    int u = t - 256;
    if (u >= 0 && u < Cb) {
        float m = Sb[u]*invB;
        float v = fmaxf(Sb[Cb+u]*invB - m*m, 0.f);
        float sc = gb[u]*rsqrtf(v + 1e-5f);
        SSb[u] = sc;
        SSb[Cb+u] = fmaf(-m, sc, bb[u]);
    }
}

// ---------------- layer 0 edge MLP: stats pass ----------------
__global__ __launch_bounds__(256) void k_edge_stats(const float* __restrict__ xf,
                                                    const int* __restrict__ ei,
                                                    const float* __restrict__ W,
                                                    float* __restrict__ S) {
    __shared__ float w[256];
    __shared__ float red[64];
    int tid = threadIdx.x;
    w[tid] = W[tid];
    if (tid < 64) red[tid] = 0.f;
    __syncthreads();
    float s[32], q[32];
#pragma unroll
    for (int c = 0; c < 32; ++c) { s[c] = 0.f; q[c] = 0.f; }
    for (int e = blockIdx.x*256 + tid; e < EG; e += gridDim.x*256) {
        int b = e >> 17, j = e & (EE-1);
        const int* base = ei + (size_t)b*2*EE;
        int ctr = base[j], nbr = base[EE + j];
        const float4* pc = (const float4*)(xf + ((size_t)(b<<14) + ctr)*8);
        const float4* pn = (const float4*)(xf + ((size_t)(b<<14) + nbr)*8);
        float4 c0 = pc[0], c1 = pc[1], n0 = pn[0], n1 = pn[1];
        float d[8] = {n0.x-c0.x, n0.y-c0.y, n0.z-c0.z, n0.w-c0.w,
                      n1.x-c1.x, n1.y-c1.y, n1.z-c1.z, n1.w-c1.w};
#pragma unroll
        for (int c = 0; c < 32; ++c) {
            float z = 0.f;
#pragma unroll
            for (int k = 0; k < 8; ++k) z = fmaf(d[k], w[k*32+c], z);
            s[c] += z; q[c] = fmaf(z, z, q[c]);
        }
    }
#pragma unroll
    for (int off = 32; off >= 1; off >>= 1) {
#pragma unroll
        for (int c = 0; c < 32; ++c) {
            s[c] += __shfl_xor(s[c], off, 64);
            q[c] += __shfl_xor(q[c], off, 64);
        }
    }
    if ((tid & 63) == 0) {
#pragma unroll
        for (int c = 0; c < 32; ++c) { atomicAdd(&red[c], s[c]); atomicAdd(&red[32+c], q[c]); }
    }
    __syncthreads();
    if (tid < 64) atomicAdd(&S[tid], red[tid]);
}

// ---- layer 0 edge apply: BNa(x0raw fp16)+lrelu + edge MLP max, write x0 final fp16 ----
__global__ __launch_bounds__(256) void k_edge_apply(const float* __restrict__ xf,
                                                    const int* __restrict__ ei,
                                                    const float* __restrict__ W,
                                                    const float* __restrict__ SSa,
                                                    const float* __restrict__ SSb,
                                                    unsigned short* __restrict__ x0) {
    __shared__ float w[256];
    __shared__ float scb[32], shb[32], sca[32], sha[32];
    int tid = threadIdx.x;
    w[tid] = W[tid];
    if (tid < 32) {
        scb[tid] = SSb[tid]; shb[tid] = SSb[32+tid];
        sca[tid] = SSa[tid]; sha[tid] = SSa[32+tid];
    }
    __syncthreads();
    int r = blockIdx.x*256 + tid;
    int b = r >> 14, n = r & (NN-1);
    const int* nb = ei + (size_t)b*2*EE + EE + n*KK;
    const float4* pc = (const float4*)(xf + (size_t)r*8);
    float4 c0 = pc[0], c1 = pc[1];
    float mx[32];
#pragma unroll
    for (int c = 0; c < 32; ++c) mx[c] = -3.0e38f;
    for (int k = 0; k < KK; ++k) {
        int j = nb[k];
        const float4* pn = (const float4*)(xf + ((size_t)(b<<14) + j)*8);
        float4 n0 = pn[0], n1 = pn[1];
        float d[8] = {n0.x-c0.x, n0.y-c0.y, n0.z-c0.z, n0.w-c0.w,
                      n1.x-c1.x, n1.y-c1.y, n1.z-c1.z, n1.w-c1.w};
#pragma unroll
        for (int c = 0; c < 32; ++c) {
            float z = 0.f;
#pragma unroll
            for (int k2 = 0; k2 < 8; ++k2) z = fmaf(d[k2], w[k2*32+c], z);
            float y = lrelu(fmaf(z, scb[c], shb[c]));
            mx[c] = fmaxf(mx[c], y);
        }
    }
    ushort8v* xp = (ushort8v*)(x0 + (size_t)r*32);
#pragma unroll
    for (int i = 0; i < 4; ++i) {
        ushort8v v = xp[i];
        ushort8v o;
#pragma unroll
        for (int j = 0; j < 8; ++j) {
            int c = i*8 + j;
            o[j] = f2h(lrelu(fmaf(h2f(v[j]), sca[c], sha[c])) + mx[c]);
        }
        xp[i] = o;
    }
}

// ---- weight prep: pack Wa|Wb into MFMA B-fragment order, single fp16 plane ----
template<int CI, int CO>
__global__ __launch_bounds__(256) void k_packW(const float* __restrict__ Wa,
                                               const float* __restrict__ Wb,
                                               unsigned short* __restrict__ Wp) {
    constexpr int NT = 2*CO;
    constexpr int KT = CI/32;
    int t = blockIdx.x*256 + threadIdx.x;
    if (t >= NT*CI) return;
    int ng = t % NT, k = t / NT;
    float v = (ng < CO) ? Wa[(size_t)k*CO + ng] : Wb[(size_t)k*CO + (ng - CO)];
    int nt = ng >> 4, n = ng & 15;
    int kt = k >> 5, kq = (k & 31) >> 3, j = k & 7;
    int f = nt*KT + kt;
    int idx = f*512 + (((kq*16 + n) ^ (2*(f&3)))<<3) + j;
    Wp[idx] = f2h(v);
}

// ---- fused dual MFMA GEMM (fp16 in/out): BM=64, IT=2 (32 AGPR acc) for 4 waves/SIMD ----
template<int CI, int CO>
__global__ __launch_bounds__(256, 4) void k_mfma_dual(const unsigned short* __restrict__ X,
                                                      const unsigned short* __restrict__ Wp,
                                                      unsigned short* __restrict__ Za,
                                                      unsigned short* __restrict__ Zb,
                                                      float* __restrict__ Sa,
                                                      float* __restrict__ Sb) {
    constexpr int BM = 64;
    constexpr int KT = CI/32;
    constexpr int IT = BM/32;          // = 2 m-tiles per wave
    constexpr int PLANE = BM*CI;       // fp16 X plane (ushorts)
    __shared__ unsigned short Xs[PLANE];
    int tid = threadIdx.x;
    int lane = tid & 63, wid = tid >> 6;
    int wm = wid & 1, wn = (wid >> 1) & 1;
    int ch = blockIdx.y;
    size_t rowbase = (size_t)blockIdx.x * BM;
    // ---- stage X (fp16 global, 16B/lane) -> fragment-packed LDS ----
    constexpr int U8PR = CI/8;
    for (int u = tid; u < BM*U8PR; u += 256) {
        int r = u / U8PR, k0 = (u % U8PR)*8;
        ushort8v v = *(const ushort8v*)&X[(rowbase + r)*CI + k0];
        int mt = r >> 4, m = r & 15;
        int kt = k0 >> 5, kq = (k0 & 31) >> 3;
        int f = mt*KT + kt;
        int idx = f*512 + (((kq*16 + m) ^ (2*(f&3)))<<3);
        *(ushort8v*)&Xs[idx] = v;
    }
    __syncthreads();
    float4v acc[IT][4];
#pragma unroll
    for (int i = 0; i < IT; ++i)
#pragma unroll
        for (int j = 0; j < 4; ++j)
            acc[i][j] = (float4v){0.f, 0.f, 0.f, 0.f};
#pragma unroll
    for (int kt = 0; kt < KT; ++kt) {
        half8v ah[IT], wv[4];
#pragma unroll
        for (int i = 0; i < IT; ++i) {
            int f = (wm*IT + i)*KT + kt;
            int off = f*512 + ((lane ^ (2*(f&3)))<<3);
            ah[i] = *(const half8v*)&Xs[off];
        }
#pragma unroll
        for (int j = 0; j < 4; ++j) {
            int fw = (ch*8 + wn*4 + j)*KT + kt;
            int offw = fw*512 + ((lane ^ (2*(fw&3)))<<3);
            wv[j] = *(const half8v*)&Wp[offw];
        }
#pragma unroll
        for (int i = 0; i < IT; ++i)
#pragma unroll
            for (int j = 0; j < 4; ++j)
                acc[i][j] = __builtin_amdgcn_mfma_f32_16x16x32_f16(ah[i], wv[j], acc[i][j], 0, 0, 0);
    }
    // ---- epilogue: fp16 store + stats per n-tile ----
#pragma unroll
    for (int j = 0; j < 4; ++j) {
        int ntg = ch*8 + wn*4 + j;
        int ngbase = ntg*16;
        bool isA = (ngbase < CO);
        int col = (isA ? ngbase : ngbase - CO) + (lane & 15);
        unsigned short* Z = isA ? Za : Zb;
        float s = 0.f, q = 0.f;
#pragma unroll
        for (int i = 0; i < IT; ++i) {
#pragma unroll
            for (int reg = 0; reg < 4; ++reg) {
                float vv = acc[i][j][reg];
                size_t row = rowbase + (size_t)(wm*(IT*16) + i*16 + ((lane>>4)<<2) + reg);
                Z[row*CO + col] = f2h(vv);
                s += vv; q = fmaf(vv, vv, q);
            }
        }
        s += __shfl_xor(s, 16, 64); q += __shfl_xor(q, 16, 64);
        s += __shfl_xor(s, 32, 64); q += __shfl_xor(q, 32, 64);
        if (lane < 16) {
            float* Sg = isA ? Sa : Sb;
            atomicAdd(&Sg[col], s);
            atomicAdd(&Sg[CO + col], q);
        }
    }
}

// ---- fused: BNa+lrelu on center row (fp16), gather 8 nbrs fp16 w/ BNb+lrelu, max, add ----
template<int CO>
__global__ __launch_bounds__(256) void k_gathermax(unsigned short* __restrict__ xi,
                                                   const unsigned short* __restrict__ zbh,
                                                   const int* __restrict__ ei,
                                                   const float* __restrict__ SSa,
                                                   const float* __restrict__ SSb) {
    constexpr int CQ = CO/8;
    int t = blockIdx.x*256 + threadIdx.x;
    int r = t / CQ;
    int c8 = (t % CQ)*8;
    int b = r >> 14, n = r & (NN-1);
    const int* nb = ei + (size_t)b*2*EE + EE + n*KK;
    float sb[8], hb[8];
#pragma unroll
    for (int j = 0; j < 8; ++j) { sb[j] = SSb[c8+j]; hb[j] = SSb[CO+c8+j]; }
    int nbr[KK];
#pragma unroll
    for (int k = 0; k < KK; ++k) nbr[k] = nb[k];
    size_t bbase = ((size_t)(b<<14))*CO + c8;
    float mx[8];
#pragma unroll
    for (int j = 0; j < 8; ++j) mx[j] = -3e38f;
#pragma unroll
    for (int k = 0; k < KK; ++k) {
        ushort8v u = *(const ushort8v*)(zbh + bbase + (size_t)nbr[k]*CO);
#pragma unroll
        for (int j = 0; j < 8; ++j)
            mx[j] = fmaxf(mx[j], lrelu(fmaf(h2f(u[j]), sb[j], hb[j])));
    }
    ushort8v* xp = (ushort8v*)(xi + (size_t)r*CO + c8);
    ushort8v a = *xp;
    ushort8v o;
#pragma unroll
    for (int j = 0; j < 8; ++j) {
        float sa = SSa[c8+j], ha = SSa[CO+c8+j];
        o[j] = f2h(lrelu(fmaf(h2f(a[j]), sa, ha)) + mx[j]);
    }
    *xp = o;
}

// ---------------- concat @ Wcat dot (one wave per row, fp16 tables) ----------------
__global__ __launch_bounds__(256) void k_catdot(const unsigned short* __restrict__ x0,
                                                const unsigned short* __restrict__ x1,
                                                const unsigned short* __restrict__ x2,
                                                const unsigned short* __restrict__ x3,
                                                const float* __restrict__ Wc,
                                                float* __restrict__ zc) {
    int r = blockIdx.x*4 + (threadIdx.x >> 6);
    int l = threadIdx.x & 63;
    float s = 0.f;
    if (l < 32) s = h2f(x0[(size_t)r*32 + l])*Wc[l];
    s = fmaf(h2f(x1[(size_t)r*64 + l]), Wc[32+l], s);
    s = fmaf(h2f(x2[(size_t)r*128 + l]),      Wc[96+l],  s);
    s = fmaf(h2f(x2[(size_t)r*128 + 64 + l]), Wc[160+l], s);
#pragma unroll
    for (int qd = 0; qd < 4; ++qd)
        s = fmaf(h2f(x3[(size_t)r*256 + qd*64 + l]), Wc[224 + qd*64 + l], s);
#pragma unroll
    for (int off = 32; off >= 1; off >>= 1) s += __shfl_xor(s, off, 64);
    if (l == 0) zc[r] = s;
}

// ---------------- final: BN(1 col) + leaky + bias ----------------
__global__ __launch_bounds__(256) void k_catfinal(const float* __restrict__ zc,
                                                  const float* __restrict__ S,
                                                  const float* __restrict__ g,
                                                  const float* __restrict__ bb,
                                                  const float* __restrict__ bias,
                                                  float* __restrict__ out) {
    int r = blockIdx.x*256 + threadIdx.x;
    const float invR = 1.f/65536.f;
    float m = S[0]*invR;
    float v = fmaxf(S[1]*invR - m*m, 0.f);
    float sc = g[0]*rsqrtf(v + 1e-5f);
    float sh = fmaf(-m, sc, bb[0]);
    float y = lrelu(fmaf(zc[r], sc, sh));
    out[r] = y + bias[0];
}

extern "C" void kernel_launch(void* const* d_in, const int* in_sizes, int n_in,
                              void* d_out, int out_size, void* d_ws, size_t ws_size,
                              hipStream_t stream) {
    const float* x    = (const float*)d_in[0];
    const int*   ei   = (const int*)d_in[1];
    const float* W0a  = (const float*)d_in[2];
    const float* g0a  = (const float*)d_in[3];
    const float* b0a  = (const float*)d_in[4];
    const float* W0b  = (const float*)d_in[5];
    const float* g0b  = (const float*)d_in[6];
    const float* b0b  = (const float*)d_in[7];
    const float* W1a  = (const float*)d_in[8];
    const float* g1a  = (const float*)d_in[9];
    const float* b1a  = (const float*)d_in[10];
    const float* W1b  = (const float*)d_in[11];
    const float* g1b  = (const float*)d_in[12];
    const float* b1b  = (const float*)d_in[13];
    const float* W2a  = (const float*)d_in[14];
    const float* g2a  = (const float*)d_in[15];
    const float* b2a  = (const float*)d_in[16];
    const float* W2b  = (const float*)d_in[17];
    const float* g2b  = (const float*)d_in[18];
    const float* b2b  = (const float*)d_in[19];
    const float* W3a  = (const float*)d_in[20];
    const float* g3a  = (const float*)d_in[21];
    const float* b3a  = (const float*)d_in[22];
    const float* W3b  = (const float*)d_in[23];
    const float* g3b  = (const float*)d_in[24];
    const float* b3b  = (const float*)d_in[25];
    const float* Wcat = (const float*)d_in[26];
    const float* gcat = (const float*)d_in[27];
    const float* bcat = (const float*)d_in[28];
    const float* bias = (const float*)d_in[29];
    float* out = (float*)d_out;

    float* ws = (float*)d_ws;
    unsigned short* x0 = (unsigned short*)(ws + OFF_X0);
    unsigned short* x1 = (unsigned short*)(ws + OFF_X1);
    unsigned short* x2 = (unsigned short*)(ws + OFF_X2);
    unsigned short* x3 = (unsigned short*)(ws + OFF_X3);
    unsigned short* zbh = (unsigned short*)(ws + OFF_ZB);
    float* zc = ws + OFF_ZC;
    float* S  = ws + OFF_S;
    float* SS = ws + OFF_SS;
    unsigned short* wpbase = (unsigned short*)(ws + OFF_WP);
    unsigned short* wp1 = wpbase + WP1_OFF;
    unsigned short* wp2 = wpbase + WP2_OFF;
    unsigned short* wp3 = wpbase + WP3_OFF;
    auto Sl  = [&](int i) { return S  + i*512; };
    auto SSl = [&](int i) { return SS + i*512; };

    const float invR = 1.f/(float)RR;
    const float invE = 1.f/(float)EG;

    hipMemsetAsync(S, 0, 9*512*sizeof(float), stream);

    // ---- weight prep (tiny, independent) ----
    k_packW<32,64><<<(128*32+255)/256, 256, 0, stream>>>(W1a, W1b, wp1);
    k_packW<64,128><<<(256*64+255)/256, 256, 0, stream>>>(W2a, W2b, wp2);
    k_packW<128,256><<<(512*128+255)/256, 256, 0, stream>>>(W3a, W3b, wp3);

    // ---- layer 0 ----
    k_l0_node<<<RR/256, 256, 0, stream>>>(x, W0a, x0, Sl(0));
    k_edge_stats<<<256, 256, 0, stream>>>(x, ei, W0b, Sl(1));
    k_finalize2<<<1, 512, 0, stream>>>(Sl(0), g0a, b0a, invR, SSl(0), 32,
                                       Sl(1), g0b, b0b, invE, SSl(1), 32);
    k_edge_apply<<<RR/256, 256, 0, stream>>>(x, ei, W0b, SSl(0), SSl(1), x0);

    // ---- layer 1: 32 -> 64 (BM=64, 1024 blocks) ----
    k_mfma_dual<32,64><<<dim3(RR/64,1), 256, 0, stream>>>(x0, wp1, x1, zbh, Sl(2), Sl(3));
    k_finalize2<<<1, 512, 0, stream>>>(Sl(2), g1a, b1a, invR, SSl(2), 64,
                                       Sl(3), g1b, b1b, invR, SSl(3), 64);
    k_gathermax<64><<<RR*8/256, 256, 0, stream>>>(x1, zbh, ei, SSl(2), SSl(3));

    // ---- layer 2: 64 -> 128 (chunk-split x2) ----
    k_mfma_dual<64,128><<<dim3(RR/64,2), 256, 0, stream>>>(x1, wp2, x2, zbh, Sl(4), Sl(5));
    k_finalize2<<<1, 512, 0, stream>>>(Sl(4), g2a, b2a, invR, SSl(4), 128,
                                       Sl(5), g2b, b2b, invR, SSl(5), 128);
    k_gathermax<128><<<RR*16/256, 256, 0, stream>>>(x2, zbh, ei, SSl(4), SSl(5));

    // ---- layer 3: 128 -> 256 (chunk-split x4) ----
    k_mfma_dual<128,256><<<dim3(RR/64,4), 256, 0, stream>>>(x2, wp3, x3, zbh, Sl(6), Sl(7));
    k_finalize2<<<1, 512, 0, stream>>>(Sl(6), g3a, b3a, invR, SSl(6), 256,
                                       Sl(7), g3b, b3b, invR, SSl(7), 256);
    k_gathermax<256><<<RR*32/256, 256, 0, stream>>>(x3, zbh, ei, SSl(6), SSl(7));

    // ---- cat head ----
    k_catdot<<<RR/4, 256, 0, stream>>>(x0, x1, x2, x3, Wcat, zc);
    k_colstats<1><<<512, 256, 0, stream>>>(zc, RR, Sl(8));
    k_catfinal<<<RR/256, 256, 0, stream>>>(zc, Sl(8), gcat, bcat, bias, out);
}

// Round 7
// 412.161 us; speedup vs baseline: 1.2978x; 1.2978x over previous
//
#include <hip/hip_runtime.h>
#include <math.h>

// Problem constants
static constexpr int BB = 4;        // batch
static constexpr int NN = 16384;    // nodes per batch
static constexpr int KK = 8;        // neighbors per node
static constexpr int EE = 131072;   // edges per batch = NN*KK
static constexpr int RR = 65536;    // BB*NN rows
static constexpr int EG = 524288;   // BB*EE edges total

// Workspace layout (float offsets — regions sized for fp32 era, fp16 uses half)
static constexpr size_t OFF_X0 = 0;
static constexpr size_t OFF_X1 = OFF_X0 + (size_t)RR*32;
static constexpr size_t OFF_X2 = OFF_X1 + (size_t)RR*64;
static constexpr size_t OFF_X3 = OFF_X2 + (size_t)RR*128;
static constexpr size_t OFF_ZB = OFF_X3 + (size_t)RR*256; // fp16 b-branch
static constexpr size_t OFF_ZC = OFF_ZB + (size_t)RR*128; // 65536 fp32
static constexpr size_t OFF_S  = OFF_ZC + (size_t)RR;     // 9 slots * 512
static constexpr size_t OFF_SS = OFF_S + 9*512;           // 9 slots * 512
static constexpr size_t OFF_WP = OFF_SS + 9*512;          // packed fp16 weights (ushort)
static constexpr size_t WP1_OFF = 0;               // 128*32   = 4096
static constexpr size_t WP2_OFF = 4096;            // 256*64   = 16384
static constexpr size_t WP3_OFF = 4096 + 16384;    // 512*128  = 65536

__device__ __forceinline__ float lrelu(float x) { return fmaxf(x, 0.2f*x); }

__device__ __forceinline__ unsigned short f2h(float f) {
    _Float16 h = (_Float16)f;
    return *(unsigned short*)&h;
}
__device__ __forceinline__ float h2f(unsigned short u) {
    _Float16 h = *(_Float16*)&u;
    return (float)h;
}

typedef __attribute__((ext_vector_type(8))) _Float16 half8v;
typedef __attribute__((ext_vector_type(8))) unsigned short ushort8v;
typedef __attribute__((ext_vector_type(4))) float float4v;

// ---------------- layer 0: node GEMM 8->32 (pre-BN, fp16 out) + fused col stats ----------------
__global__ __launch_bounds__(256) void k_l0_node(const float* __restrict__ xf,
                                                 const float* __restrict__ W,
                                                 unsigned short* __restrict__ z,
                                                 float* __restrict__ S) {
    __shared__ float w[256];
    __shared__ float red[64];
    int tid = threadIdx.x;
    w[tid] = W[tid];
    if (tid < 64) red[tid] = 0.f;
    __syncthreads();
    int r = blockIdx.x*256 + tid;
    const float4* xr = (const float4*)(xf + (size_t)r*8);
    float4 a = xr[0], b = xr[1];
    float xv[8] = {a.x,a.y,a.z,a.w,b.x,b.y,b.z,b.w};
    float op[32];
#pragma unroll
    for (int c = 0; c < 32; ++c) {
        float s = 0.f;
#pragma unroll
        for (int k = 0; k < 8; ++k) s = fmaf(xv[k], w[k*32+c], s);
        op[c] = s;
    }
    ushort8v* zp = (ushort8v*)(z + (size_t)r*32);
#pragma unroll
    for (int i = 0; i < 4; ++i) {
        ushort8v h;
#pragma unroll
        for (int j = 0; j < 8; ++j) h[j] = f2h(op[i*8+j]);
        zp[i] = h;
    }
#pragma unroll
    for (int c = 0; c < 32; ++c) {
        float s = op[c], q = op[c]*op[c];
#pragma unroll
        for (int off = 32; off >= 1; off >>= 1) {
            s += __shfl_xor(s, off, 64);
            q += __shfl_xor(q, off, 64);
        }
        if ((tid & 63) == 0) { atomicAdd(&red[c], s); atomicAdd(&red[32+c], q); }
    }
    __syncthreads();
    if (tid < 64) atomicAdd(&S[tid], red[tid]);
}

// ---------------- column stats (only for the 1-col cat head) ----------------
template<int C>
__global__ __launch_bounds__(256) void k_colstats(const float* __restrict__ Z, int R,
                                                  float* __restrict__ S) {
    constexpr int TPC = 256 / C;
    __shared__ float ls[256];
    __shared__ float lq[256];
    int tid = threadIdx.x;
    int c = tid % C, rr = tid / C;
    float s = 0.f, q = 0.f;
    for (int r = blockIdx.x*TPC + rr; r < R; r += gridDim.x*TPC) {
        float v = Z[(size_t)r*C + c];
        s += v; q = fmaf(v, v, q);
    }
    ls[tid] = s; lq[tid] = q;
    __syncthreads();
#pragma unroll
    for (int half = TPC/2; half >= 1; half >>= 1) {
        if (rr < half) { ls[tid] += ls[tid + half*C]; lq[tid] += lq[tid + half*C]; }
        __syncthreads();
    }
    if (rr == 0) { atomicAdd(&S[c], ls[tid]); atomicAdd(&S[C+c], lq[tid]); }
}

// ---------------- finalize (two BN slots in one launch) ----------------
__global__ void k_finalize2(const float* __restrict__ Sa, const float* __restrict__ ga,
                            const float* __restrict__ ba, float invA,
                            float* __restrict__ SSa, int Ca,
                            const float* __restrict__ Sb, const float* __restrict__ gb,
                            const float* __restrict__ bb, float invB,
                            float* __restrict__ SSb, int Cb) {
    int t = threadIdx.x;
    if (t < Ca) {
        float m = Sa[t]*invA;
        float v = fmaxf(Sa[Ca+t]*invA - m*m, 0.f);
        float sc = ga[t]*rsqrtf(v + 1e-5f);
        SSa[t] = sc;
        SSa[Ca+t] = fmaf(-m, sc, ba[t]);
    }
    int u = t - 256;
    if (u >= 0 && u < Cb) {
        float m = Sb[u]*invB;
        float v = fmaxf(Sb[Cb+u]*invB - m*m, 0.f);
        float sc = gb[u]*rsqrtf(v + 1e-5f);
        SSb[u] = sc;
        SSb[Cb+u] = fmaf(-m, sc, bb[u]);
    }
}

// ---------------- layer 0 edge MLP: stats pass ----------------
__global__ __launch_bounds__(256) void k_edge_stats(const float* __restrict__ xf,
                                                    const int* __restrict__ ei,
                                                    const float* __restrict__ W,
                                                    float* __restrict__ S) {
    __shared__ float w[256];
    __shared__ float red[64];
    int tid = threadIdx.x;
    w[tid] = W[tid];
    if (tid < 64) red[tid] = 0.f;
    __syncthreads();
    float s[32], q[32];
#pragma unroll
    for (int c = 0; c < 32; ++c) { s[c] = 0.f; q[c] = 0.f; }
    for (int e = blockIdx.x*256 + tid; e < EG; e += gridDim.x*256) {
        int b = e >> 17, j = e & (EE-1);
        const int* base = ei + (size_t)b*2*EE;
        int ctr = base[j], nbr = base[EE + j];
        const float4* pc = (const float4*)(xf + ((size_t)(b<<14) + ctr)*8);
        const float4* pn = (const float4*)(xf + ((size_t)(b<<14) + nbr)*8);
        float4 c0 = pc[0], c1 = pc[1], n0 = pn[0], n1 = pn[1];
        float d[8] = {n0.x-c0.x, n0.y-c0.y, n0.z-c0.z, n0.w-c0.w,
                      n1.x-c1.x, n1.y-c1.y, n1.z-c1.z, n1.w-c1.w};
#pragma unroll
        for (int c = 0; c < 32; ++c) {
            float z = 0.f;
#pragma unroll
            for (int k = 0; k < 8; ++k) z = fmaf(d[k], w[k*32+c], z);
            s[c] += z; q[c] = fmaf(z, z, q[c]);
        }
    }
#pragma unroll
    for (int off = 32; off >= 1; off >>= 1) {
#pragma unroll
        for (int c = 0; c < 32; ++c) {
            s[c] += __shfl_xor(s[c], off, 64);
            q[c] += __shfl_xor(q[c], off, 64);
        }
    }
    if ((tid & 63) == 0) {
#pragma unroll
        for (int c = 0; c < 32; ++c) { atomicAdd(&red[c], s[c]); atomicAdd(&red[32+c], q[c]); }
    }
    __syncthreads();
    if (tid < 64) atomicAdd(&S[tid], red[tid]);
}

// ---- layer 0 edge apply: BNa(x0raw fp16)+lrelu + edge MLP max, write x0 final fp16 ----
__global__ __launch_bounds__(256) void k_edge_apply(const float* __restrict__ xf,
                                                    const int* __restrict__ ei,
                                                    const float* __restrict__ W,
                                                    const float* __restrict__ SSa,
                                                    const float* __restrict__ SSb,
                                                    unsigned short* __restrict__ x0) {
    __shared__ float w[256];
    __shared__ float scb[32], shb[32], sca[32], sha[32];
    int tid = threadIdx.x;
    w[tid] = W[tid];
    if (tid < 32) {
        scb[tid] = SSb[tid]; shb[tid] = SSb[32+tid];
        sca[tid] = SSa[tid]; sha[tid] = SSa[32+tid];
    }
    __syncthreads();
    int r = blockIdx.x*256 + tid;
    int b = r >> 14, n = r & (NN-1);
    const int* nb = ei + (size_t)b*2*EE + EE + n*KK;
    const float4* pc = (const float4*)(xf + (size_t)r*8);
    float4 c0 = pc[0], c1 = pc[1];
    float mx[32];
#pragma unroll
    for (int c = 0; c < 32; ++c) mx[c] = -3.0e38f;
    for (int k = 0; k < KK; ++k) {
        int j = nb[k];
        const float4* pn = (const float4*)(xf + ((size_t)(b<<14) + j)*8);
        float4 n0 = pn[0], n1 = pn[1];
        float d[8] = {n0.x-c0.x, n0.y-c0.y, n0.z-c0.z, n0.w-c0.w,
                      n1.x-c1.x, n1.y-c1.y, n1.z-c1.z, n1.w-c1.w};
#pragma unroll
        for (int c = 0; c < 32; ++c) {
            float z = 0.f;
#pragma unroll
            for (int k2 = 0; k2 < 8; ++k2) z = fmaf(d[k2], w[k2*32+c], z);
            float y = lrelu(fmaf(z, scb[c], shb[c]));
            mx[c] = fmaxf(mx[c], y);
        }
    }
    ushort8v* xp = (ushort8v*)(x0 + (size_t)r*32);
#pragma unroll
    for (int i = 0; i < 4; ++i) {
        ushort8v v = xp[i];
        ushort8v o;
#pragma unroll
        for (int j = 0; j < 8; ++j) {
            int c = i*8 + j;
            o[j] = f2h(lrelu(fmaf(h2f(v[j]), sca[c], sha[c])) + mx[c]);
        }
        xp[i] = o;
    }
}

// ---- weight prep: pack Wa|Wb into MFMA B-fragment order (no swizzle) ----
// fragment f = nt*KT + kt; idx = f*512 + (kq*16 + n)*8 + j   (lane kq*16+n reads 8 ushorts)
template<int CI, int CO>
__global__ __launch_bounds__(256) void k_packW(const float* __restrict__ Wa,
                                               const float* __restrict__ Wb,
                                               unsigned short* __restrict__ Wp) {
    constexpr int NT = 2*CO;
    constexpr int KT = CI/32;
    int t = blockIdx.x*256 + threadIdx.x;
    if (t >= NT*CI) return;
    int ng = t % NT, k = t / NT;
    float v = (ng < CO) ? Wa[(size_t)k*CO + ng] : Wb[(size_t)k*CO + (ng - CO)];
    int nt = ng >> 4, n = ng & 15;
    int kt = k >> 5, kq = (k & 31) >> 3, j = k & 7;
    int f = nt*KT + kt;
    int idx = f*512 + ((kq*16 + n)<<3) + j;
    Wp[idx] = f2h(v);
}

// ---- fused dual MFMA GEMM, no X staging: A-frags direct from row-major fp16 global ----
// W chunk in LDS (contiguous, conflict-free). One barrier. LDS stats reduction.
// Block: 4 waves, each handles MR*16 rows; all share NCH n-tiles (chunk = blockIdx.y).
template<int CI, int CO, int MR, int NCH>
__global__ __launch_bounds__(256, 4) void k_mfma_dual(const unsigned short* __restrict__ X,
                                                      const unsigned short* __restrict__ Wp,
                                                      unsigned short* __restrict__ Za,
                                                      unsigned short* __restrict__ Zb,
                                                      float* __restrict__ Sa,
                                                      float* __restrict__ Sb) {
    constexpr int KT = CI/32;
    constexpr int WCNT = NCH*KT*512;   // ushorts in W chunk
    __shared__ unsigned short Wlds[WCNT];
    __shared__ float red[2*NCH*16];
    int tid = threadIdx.x;
    int lane = tid & 63, wid = tid >> 6;
    int ch = blockIdx.y;
    size_t rowbase = (size_t)blockIdx.x * (4*MR*16) + (size_t)wid*(MR*16);
    // stage W chunk (straight copy, coalesced) + zero stats
    {
        const ushort8v* src = (const ushort8v*)(Wp + (size_t)ch*WCNT);
        ushort8v* dst = (ushort8v*)Wlds;
        for (int u = tid; u < WCNT/8; u += 256) dst[u] = src[u];
        for (int u = tid; u < 2*NCH*16; u += 256) red[u] = 0.f;
    }
    __syncthreads();
    float4v acc[MR][NCH];
#pragma unroll
    for (int i = 0; i < MR; ++i)
#pragma unroll
        for (int j = 0; j < NCH; ++j)
            acc[i][j] = (float4v){0.f, 0.f, 0.f, 0.f};
    int mrow = lane & 15, kq = lane >> 4;
#pragma unroll
    for (int kt = 0; kt < KT; ++kt) {
        half8v a[MR];
#pragma unroll
        for (int i = 0; i < MR; ++i)
            a[i] = *(const half8v*)&X[(rowbase + i*16 + mrow)*CI + kt*32 + kq*8];
#pragma unroll
        for (int j = 0; j < NCH; ++j) {
            half8v w = *(const half8v*)&Wlds[(j*KT + kt)*512 + lane*8];
#pragma unroll
            for (int i = 0; i < MR; ++i)
                acc[i][j] = __builtin_amdgcn_mfma_f32_16x16x32_f16(a[i], w, acc[i][j], 0, 0, 0);
        }
    }
    // ---- epilogue: fp16 store + LDS stats ----
#pragma unroll
    for (int j = 0; j < NCH; ++j) {
        int ntg = ch*NCH + j;
        int ngbase = ntg*16;
        bool isA = (ngbase < CO);
        int col = (isA ? ngbase : ngbase - CO) + (lane & 15);
        unsigned short* Z = isA ? Za : Zb;
        float s = 0.f, q = 0.f;
#pragma unroll
        for (int i = 0; i < MR; ++i) {
#pragma unroll
            for (int reg = 0; reg < 4; ++reg) {
                float vv = acc[i][j][reg];
                size_t row = rowbase + (size_t)(i*16 + ((lane>>4)<<2) + reg);
                Z[row*CO + col] = f2h(vv);
                s += vv; q = fmaf(vv, vv, q);
            }
        }
        s += __shfl_xor(s, 16, 64); q += __shfl_xor(q, 16, 64);
        s += __shfl_xor(s, 32, 64); q += __shfl_xor(q, 32, 64);
        if (lane < 16) {
            atomicAdd(&red[j*16 + lane], s);
            atomicAdd(&red[NCH*16 + j*16 + lane], q);
        }
    }
    __syncthreads();
    // flush stats: one global atomic per (col, stat) per block
    for (int u = tid; u < NCH*16; u += 256) {
        int j = u >> 4, cl = u & 15;
        int ntg = ch*NCH + j;
        int ngbase = ntg*16;
        bool isA = (ngbase < CO);
        int col = (isA ? ngbase : ngbase - CO) + cl;
        float* Sg = isA ? Sa : Sb;
        atomicAdd(&Sg[col], red[u]);
        atomicAdd(&Sg[CO + col], red[NCH*16 + u]);
    }
}

// ---- fused: BNa+lrelu on center row (fp16), gather 8 nbrs fp16 w/ BNb+lrelu, max, add ----
template<int CO>
__global__ __launch_bounds__(256) void k_gathermax(unsigned short* __restrict__ xi,
                                                   const unsigned short* __restrict__ zbh,
                                                   const int* __restrict__ ei,
                                                   const float* __restrict__ SSa,
                                                   const float* __restrict__ SSb) {
    constexpr int CQ = CO/8;
    int t = blockIdx.x*256 + threadIdx.x;
    int r = t / CQ;
    int c8 = (t % CQ)*8;
    int b = r >> 14, n = r & (NN-1);
    const int* nb = ei + (size_t)b*2*EE + EE + n*KK;
    float sb[8], hb[8];
#pragma unroll
    for (int j = 0; j < 8; ++j) { sb[j] = SSb[c8+j]; hb[j] = SSb[CO+c8+j]; }
    int nbr[KK];
#pragma unroll
    for (int k = 0; k < KK; ++k) nbr[k] = nb[k];
    size_t bbase = ((size_t)(b<<14))*CO + c8;
    float mx[8];
#pragma unroll
    for (int j = 0; j < 8; ++j) mx[j] = -3e38f;
#pragma unroll
    for (int k = 0; k < KK; ++k) {
        ushort8v u = *(const ushort8v*)(zbh + bbase + (size_t)nbr[k]*CO);
#pragma unroll
        for (int j = 0; j < 8; ++j)
            mx[j] = fmaxf(mx[j], lrelu(fmaf(h2f(u[j]), sb[j], hb[j])));
    }
    ushort8v* xp = (ushort8v*)(xi + (size_t)r*CO + c8);
    ushort8v a = *xp;
    ushort8v o;
#pragma unroll
    for (int j = 0; j < 8; ++j) {
        float sa = SSa[c8+j], ha = SSa[CO+c8+j];
        o[j] = f2h(lrelu(fmaf(h2f(a[j]), sa, ha)) + mx[j]);
    }
    *xp = o;
}

// ---------------- concat @ Wcat dot (one wave per row, fp16 tables) ----------------
__global__ __launch_bounds__(256) void k_catdot(const unsigned short* __restrict__ x0,
                                                const unsigned short* __restrict__ x1,
                                                const unsigned short* __restrict__ x2,
                                                const unsigned short* __restrict__ x3,
                                                const float* __restrict__ Wc,
                                                float* __restrict__ zc) {
    int r = blockIdx.x*4 + (threadIdx.x >> 6);
    int l = threadIdx.x & 63;
    float s = 0.f;
    if (l < 32) s = h2f(x0[(size_t)r*32 + l])*Wc[l];
    s = fmaf(h2f(x1[(size_t)r*64 + l]), Wc[32+l], s);
    s = fmaf(h2f(x2[(size_t)r*128 + l]),      Wc[96+l],  s);
    s = fmaf(h2f(x2[(size_t)r*128 + 64 + l]), Wc[160+l], s);
#pragma unroll
    for (int qd = 0; qd < 4; ++qd)
        s = fmaf(h2f(x3[(size_t)r*256 + qd*64 + l]), Wc[224 + qd*64 + l], s);
#pragma unroll
    for (int off = 32; off >= 1; off >>= 1) s += __shfl_xor(s, off, 64);
    if (l == 0) zc[r] = s;
}

// ---------------- final: BN(1 col) + leaky + bias ----------------
__global__ __launch_bounds__(256) void k_catfinal(const float* __restrict__ zc,
                                                  const float* __restrict__ S,
                                                  const float* __restrict__ g,
                                                  const float* __restrict__ bb,
                                                  const float* __restrict__ bias,
                                                  float* __restrict__ out) {
    int r = blockIdx.x*256 + threadIdx.x;
    const float invR = 1.f/65536.f;
    float m = S[0]*invR;
    float v = fmaxf(S[1]*invR - m*m, 0.f);
    float sc = g[0]*rsqrtf(v + 1e-5f);
    float sh = fmaf(-m, sc, bb[0]);
    float y = lrelu(fmaf(zc[r], sc, sh));
    out[r] = y + bias[0];
}

extern "C" void kernel_launch(void* const* d_in, const int* in_sizes, int n_in,
                              void* d_out, int out_size, void* d_ws, size_t ws_size,
                              hipStream_t stream) {
    const float* x    = (const float*)d_in[0];
    const int*   ei   = (const int*)d_in[1];
    const float* W0a  = (const float*)d_in[2];
    const float* g0a  = (const float*)d_in[3];
    const float* b0a  = (const float*)d_in[4];
    const float* W0b  = (const float*)d_in[5];
    const float* g0b  = (const float*)d_in[6];
    const float* b0b  = (const float*)d_in[7];
    const float* W1a  = (const float*)d_in[8];
    const float* g1a  = (const float*)d_in[9];
    const float* b1a  = (const float*)d_in[10];
    const float* W1b  = (const float*)d_in[11];
    const float* g1b  = (const float*)d_in[12];
    const float* b1b  = (const float*)d_in[13];
    const float* W2a  = (const float*)d_in[14];
    const float* g2a  = (const float*)d_in[15];
    const float* b2a  = (const float*)d_in[16];
    const float* W2b  = (const float*)d_in[17];
    const float* g2b  = (const float*)d_in[18];
    const float* b2b  = (const float*)d_in[19];
    const float* W3a  = (const float*)d_in[20];
    const float* g3a  = (const float*)d_in[21];
    const float* b3a  = (const float*)d_in[22];
    const float* W3b  = (const float*)d_in[23];
    const float* g3b  = (const float*)d_in[24];
    const float* b3b  = (const float*)d_in[25];
    const float* Wcat = (const float*)d_in[26];
    const float* gcat = (const float*)d_in[27];
    const float* bcat = (const float*)d_in[28];
    const float* bias = (const float*)d_in[29];
    float* out = (float*)d_out;

    float* ws = (float*)d_ws;
    unsigned short* x0 = (unsigned short*)(ws + OFF_X0);
    unsigned short* x1 = (unsigned short*)(ws + OFF_X1);
    unsigned short* x2 = (unsigned short*)(ws + OFF_X2);
    unsigned short* x3 = (unsigned short*)(ws + OFF_X3);
    unsigned short* zbh = (unsigned short*)(ws + OFF_ZB);
    float* zc = ws + OFF_ZC;
    float* S  = ws + OFF_S;
    float* SS = ws + OFF_SS;
    unsigned short* wpbase = (unsigned short*)(ws + OFF_WP);
    unsigned short* wp1 = wpbase + WP1_OFF;
    unsigned short* wp2 = wpbase + WP2_OFF;
    unsigned short* wp3 = wpbase + WP3_OFF;
    auto Sl  = [&](int i) { return S  + i*512; };
    auto SSl = [&](int i) { return SS + i*512; };

    const float invR = 1.f/(float)RR;
    const float invE = 1.f/(float)EG;

    hipMemsetAsync(S, 0, 9*512*sizeof(float), stream);

    // ---- weight prep (tiny, independent) ----
    k_packW<32,64><<<(128*32+255)/256, 256, 0, stream>>>(W1a, W1b, wp1);
    k_packW<64,128><<<(256*64+255)/256, 256, 0, stream>>>(W2a, W2b, wp2);
    k_packW<128,256><<<(512*128+255)/256, 256, 0, stream>>>(W3a, W3b, wp3);

    // ---- layer 0 ----
    k_l0_node<<<RR/256, 256, 0, stream>>>(x, W0a, x0, Sl(0));
    k_edge_stats<<<256, 256, 0, stream>>>(x, ei, W0b, Sl(1));
    k_finalize2<<<1, 512, 0, stream>>>(Sl(0), g0a, b0a, invR, SSl(0), 32,
                                       Sl(1), g0b, b0b, invE, SSl(1), 32);
    k_edge_apply<<<RR/256, 256, 0, stream>>>(x, ei, W0b, SSl(0), SSl(1), x0);

    // ---- layer 1: 32 -> 64 — NT=8, one chunk, MR=2 (128 rows/block) ----
    k_mfma_dual<32,64,2,8><<<dim3(RR/128,1), 256, 0, stream>>>(x0, wp1, x1, zbh, Sl(2), Sl(3));
    k_finalize2<<<1, 512, 0, stream>>>(Sl(2), g1a, b1a, invR, SSl(2), 64,
                                       Sl(3), g1b, b1b, invR, SSl(3), 64);
    k_gathermax<64><<<RR*8/256, 256, 0, stream>>>(x1, zbh, ei, SSl(2), SSl(3));

    // ---- layer 2: 64 -> 128 — NT=16, 2 chunks, MR=2 ----
    k_mfma_dual<64,128,2,8><<<dim3(RR/128,2), 256, 0, stream>>>(x1, wp2, x2, zbh, Sl(4), Sl(5));
    k_finalize2<<<1, 512, 0, stream>>>(Sl(4), g2a, b2a, invR, SSl(4), 128,
                                       Sl(5), g2b, b2b, invR, SSl(5), 128);
    k_gathermax<128><<<RR*16/256, 256, 0, stream>>>(x2, zbh, ei, SSl(4), SSl(5));

    // ---- layer 3: 128 -> 256 — NT=32, 4 chunks, MR=1 (64 rows/block) ----
    k_mfma_dual<128,256,1,8><<<dim3(RR/64,4), 256, 0, stream>>>(x2, wp3, x3, zbh, Sl(6), Sl(7));
    k_finalize2<<<1, 512, 0, stream>>>(Sl(6), g3a, b3a, invR, SSl(6), 256,
                                       Sl(7), g3b, b3b, invR, SSl(7), 256);
    k_gathermax<256><<<RR*32/256, 256, 0, stream>>>(x3, zbh, ei, SSl(6), SSl(7));

    // ---- cat head ----
    k_catdot<<<RR/4, 256, 0, stream>>>(x0, x1, x2, x3, Wcat, zc);
    k_colstats<1><<<512, 256, 0, stream>>>(zc, RR, Sl(8));
    k_catfinal<<<RR/256, 256, 0, stream>>>(zc, Sl(8), gcat, bcat, bias, out);
}